// Round 7
// baseline (545.780 us; speedup 1.0000x reference)
//
// GCNTox21 fused pipeline — MI355X/gfx950.  R19: GEMM density.
// Ledger: msg4 pinned at 68us (5 variants); non-msg4 = ~312us across 11
// dispatches, structure-bound (pipeline HBM total ~630MB = 100us floor).
// R19 raises MFMA density in both GEMMs (pure scheduling, no numerics):
//  (a) k_gemm_pq2: one block computes BOTH the P- and Q-column-tile for
//      its (m0,n0): A-tile staged once (was twice), 32 MFMA per barrier
//      pair (was 16), grid 1280->640.  LDS 24KB, acc 128 VGPR.
//  (b) k_gemm_bn64<NJ>: y-tiles folded (NJ=16 for Od=256): PM staged
//      once, 16 MFMA/barrier-pair, grid 640->320.
// msg4/edge/mega/pool identical to R18 (best-known).
#include <hip/hip_runtime.h>
#include <hip/hip_bf16.h>

typedef unsigned int  uint;
typedef unsigned short ushort;
typedef float  f32x2  __attribute__((ext_vector_type(2)));
typedef float  f32x4  __attribute__((ext_vector_type(4)));
typedef __bf16 bf16x8 __attribute__((ext_vector_type(8)));

#define DEV static __device__ __forceinline__

DEV float  b2f(ushort b){ return __uint_as_float(((uint)b) << 16); }
DEV float  lo2f(uint u){ return __uint_as_float(u << 16); }
DEV float  hi2f(uint u){ return __uint_as_float(u & 0xffff0000u); }
DEV ushort f2b(float f){           // RNE float->bf16
  uint u = __float_as_uint(f);
  u += 0x7fffu + ((u >> 16) & 1u);
  return (ushort)(u >> 16);
}
DEV uint pk2(float a, float b){ return (uint)f2b(a) | ((uint)f2b(b) << 16); }
DEV void unpack8(uint4 v, float* f){
  f[0]=lo2f(v.x); f[1]=hi2f(v.x); f[2]=lo2f(v.y); f[3]=hi2f(v.y);
  f[4]=lo2f(v.z); f[5]=hi2f(v.z); f[6]=lo2f(v.w); f[7]=hi2f(v.w);
}
DEV int ld_idx(const void* p, int flag, long long i){
  return flag ? ((const int*)p)[i] : (int)((const long long*)p)[i];
}
DEV float ldf(const void* p, int f, int i){
  return f ? ((const float*)p)[i] : b2f(((const ushort*)p)[i]);
}
DEV int clampi(int v, int lo, int hi){ return v < lo ? lo : (v > hi ? hi : v); }

// async 16B global -> LDS (DMA).  LDS dest = wave-uniform base + lane*16.
DEV void ld16(const ushort* g, ushort* l){
  __builtin_amdgcn_global_load_lds(
      (const __attribute__((address_space(1))) void*)g,
      (__attribute__((address_space(3))) void*)l, 16, 0, 0);
}

// ---------- zero (deg+fill) + probes in one launch ----------
__global__ __launch_bounds__(256) void k_zero_probe(const uint* __restrict__ ei,
    const uint* __restrict__ xw, int* __restrict__ iflag, int* __restrict__ fflag,
    int* __restrict__ zbase, int zn){
  int i = blockIdx.x*256 + threadIdx.x;
  if (i < zn) zbase[i] = 0;
  if (blockIdx.x == 0){
    __shared__ int anyI, cntF;
    if (threadIdx.x == 0){ anyI = 0; cntF = 0; }
    __syncthreads();
    int li = 0, lc = 0;
    for (int k = threadIdx.x; k < 1024; k += 256){
      if (ei[2*k + 1] != 0u) li = 1;            // int64 => odd words all 0
      float f = fabsf(__uint_as_float(xw[k]));  // fp32 N(0,1) words decode sane
      if (f > 1e-6f && f < 1e6f) lc++;
    }
    if (li) atomicOr(&anyI, 1);
    atomicAdd(&cntF, lc);
    __syncthreads();
    if (threadIdx.x == 0){ *iflag = anyI; *fflag = (2*cntF > 1024) ? 1 : 0; }
  }
}

// ---------- CSR count + scan ----------
__global__ __launch_bounds__(256) void k_count(const void* __restrict__ ei,
    const int* __restrict__ flag, int* __restrict__ cnt, int E, int N){
  int e = blockIdx.x*256 + threadIdx.x;
  if (e >= E) return;
  int d = clampi(ld_idx(ei, *flag, (long long)E + e), 0, N-1);
  atomicAdd(&cnt[d], 1);
}

__global__ __launch_bounds__(1024) void k_scan(const int* __restrict__ deg, int* __restrict__ rp, int n){
  __shared__ int part[1024];
  int t = threadIdx.x;
  int chunk = (n + 1023) >> 10;
  int base = t * chunk;
  int s = 0;
  for (int i = 0; i < chunk; i++){ int j = base + i; if (j < n) s += deg[j]; }
  part[t] = s;
  __syncthreads();
  for (int off = 1; off < 1024; off <<= 1){
    int v = (t >= off) ? part[t - off] : 0;
    __syncthreads();
    part[t] += v;
    __syncthreads();
  }
  int run = part[t] - s;
  for (int i = 0; i < chunk; i++){ int j = base + i; if (j < n){ rp[j] = run; run += deg[j]; } }
  if (t == 1023) rp[n] = part[1023];
}

// ---------- mega: CSR-fill + weight-cvt + node-enc ----------
struct CvtTab { const void* src[6]; ushort* dst[6]; int n[6]; int bstart[6]; int nseg; };

__global__ __launch_bounds__(256) void k_mega(
    const void* __restrict__ ei, const int* __restrict__ iflag,
    const int* __restrict__ rp, int* __restrict__ fill, int2* __restrict__ cpair,
    CvtTab ct, const int* __restrict__ fflag,
    const void* __restrict__ x, const void* __restrict__ nw, const void* __restrict__ nbias,
    ushort* __restrict__ h,
    int E, int N, int FB, int CB){
  int b = blockIdx.x;
  int t = threadIdx.x;
  if (b < FB){
    // ---- CSR fill ----
    int e = b*256 + t;
    if (e >= E) return;
    int f = *iflag;
    int s = clampi(ld_idx(ei, f, e), 0, N-1);
    int d = clampi(ld_idx(ei, f, (long long)E + e), 0, N-1);
    int pos = clampi(rp[d] + atomicAdd(&fill[d], 1), 0, E-1);
    cpair[pos] = make_int2(s, e);
  } else if (b < FB + CB){
    // ---- weight conversion (w1 x3, w2 x3) ----
    int cb = b - FB;
    int s = ct.nseg - 1;
    for (int i = 1; i < ct.nseg; i++) if (cb < ct.bstart[i]){ s = i - 1; break; }
    int rel = cb - ct.bstart[s];
    const void* sp = ct.src[s];
    ushort* d = ct.dst[s];
    int f = *fflag;
    int end = ct.n[s]; int cap = rel*8192 + 8192; if (cap < end) end = cap;
    for (int i = rel*8192 + t; i < end; i += 256)
      d[i] = f ? f2b(((const float*)sp)[i]) : ((const ushort*)sp)[i];
  } else {
    // ---- node encoder: h = relu(x @ nw.T + nb), 4 nodes/block ----
    __shared__ float xs[4][32];
    int f = *fflag;
    int nb = (b - FB - CB)*4;
    if (t < 128){
      int ni = t >> 5, ci = t & 31;
      int n = nb + ni; if (n >= N) n = N - 1;
      xs[ni][ci] = f ? ((const float*)x)[(size_t)n*32 + ci]
                     : b2f(((const ushort*)x)[(size_t)n*32 + ci]);
    }
    __syncthreads();
    float wr[32];
    if (f){
      const float4* wp = (const float4*)((const float*)nw + (size_t)t*32);
      #pragma unroll
      for (int q4 = 0; q4 < 8; q4++){
        float4 v = wp[q4];
        wr[q4*4+0]=v.x; wr[q4*4+1]=v.y; wr[q4*4+2]=v.z; wr[q4*4+3]=v.w;
      }
    } else {
      const uint4* wp = (const uint4*)((const ushort*)nw + (size_t)t*32);
      unpack8(wp[0], wr); unpack8(wp[1], wr+8); unpack8(wp[2], wr+16); unpack8(wp[3], wr+24);
    }
    float bv = ldf(nbias, f, t);
    #pragma unroll
    for (int ni = 0; ni < 4; ni++){
      int n = nb + ni;
      if (n >= N) break;
      float s = bv;
      #pragma unroll
      for (int k = 0; k < 32; k++) s += xs[ni][k]*wr[k];
      h[(size_t)n*256 + t] = f2b(fmaxf(s, 0.f));
    }
  }
}

// ---------- fused edge-encoder + reorder ----------
__global__ __launch_bounds__(256) void k_edge(const int2* __restrict__ cpair,
    const void* __restrict__ ea, const void* __restrict__ eew, const void* __restrict__ eeb,
    const int* __restrict__ fflag, float* __restrict__ ehp, int E){
  __shared__ float ws[128];
  __shared__ float bs[16];
  int f = *fflag;
  int t = threadIdx.x;
  if (t < 128) ws[t] = ldf(eew, f, t);
  if (t < 16)  bs[t] = ldf(eeb, f, t);
  __syncthreads();
  int pos = blockIdx.x*256 + t;
  if (pos >= E) return;
  int e = cpair[pos].y;
  float a[8];
  if (f){
    const float4* ap = (const float4*)((const float*)ea + (size_t)e*8);
    float4 v0 = ap[0], v1 = ap[1];
    a[0]=v0.x; a[1]=v0.y; a[2]=v0.z; a[3]=v0.w;
    a[4]=v1.x; a[5]=v1.y; a[6]=v1.z; a[7]=v1.w;
  } else {
    uint4 av = *(const uint4*)((const ushort*)ea + (size_t)e*8);
    unpack8(av, a);
  }
  float o[16];
  #pragma unroll
  for (int c = 0; c < 16; c++){
    float s = bs[c];
    #pragma unroll
    for (int j = 0; j < 8; j++) s += a[j]*ws[c*8+j];
    o[c] = fmaxf(s, 0.f);
  }
  f32x4* op = (f32x4*)(ehp + (size_t)pos*16);
  #pragma unroll
  for (int q4 = 0; q4 < 4; q4++){
    f32x4 v = {o[q4*4+0], o[q4*4+1], o[q4*4+2], o[q4*4+3]};
    op[q4] = v;
  }
}

// ---------- 128x128 GEMM producing BOTH P and Q tiles per block ----------
// A-tile staged once; per k-step 6 ld16 + 32 MFMA (2x density of R18).
// XCD-affine remap: blocks sharing an A-tile get ids === same (mod 8).
__global__ __launch_bounds__(256) void k_gemm_pq2(const ushort* __restrict__ A,
    const ushort* __restrict__ w1, int M, int Nc,
    ushort* __restrict__ P, ushort* __restrict__ Q){
  const int MT = (M + 127) >> 7;
  const int YC = Nc >> 7;            // 4 (C=512) / 2 (C=256)
  int jb = blockIdx.x;
  int gx = jb & 7, rr = jb >> 3;
  int sx = rr / YC, yy = rr % YC;
  const int Tm = sx*8 + gx;
  if (Tm >= MT) return;
  __shared__ ushort As[128*32];
  __shared__ ushort BsP[128*32];
  __shared__ ushort BsQ[128*32];
  const int t = threadIdx.x;
  const int lane = t & 63;
  const int wv = t >> 6;
  const int m0 = Tm*128;
  const int n0 = yy*128;
  const int lr = lane & 15;
  const int qq = lane >> 4;
  int srow0 = t >> 2,         sq0 = t & 3;
  int srow1 = (256 + t) >> 2, sq1 = t & 3;
  int ga0 = m0 + srow0; if (ga0 >= M) ga0 = M - 1;
  int ga1 = m0 + srow1; if (ga1 >= M) ga1 = M - 1;
  f32x4 accP[2][8], accQ[2][8];
  #pragma unroll
  for (int f = 0; f < 2; f++)
    #pragma unroll
    for (int j = 0; j < 8; j++){ accP[f][j] = {0.f,0.f,0.f,0.f}; accQ[f][j] = {0.f,0.f,0.f,0.f}; }
  for (int k0 = 0; k0 < 256; k0 += 32){
    ld16(A + (size_t)ga0*256 + k0 + sq0*8, &As[(size_t)t*8]);
    ld16(A + (size_t)ga1*256 + k0 + sq1*8, &As[(size_t)(256+t)*8]);
    // w1 row c = [P-w(256) | Q-w(256) | eh-w(16)]; same rows, two col slices
    ld16(w1 + (size_t)(n0 + srow0)*528 + k0 + sq0*8,       &BsP[(size_t)t*8]);
    ld16(w1 + (size_t)(n0 + srow1)*528 + k0 + sq1*8,       &BsP[(size_t)(256+t)*8]);
    ld16(w1 + (size_t)(n0 + srow0)*528 + 256 + k0 + sq0*8, &BsQ[(size_t)t*8]);
    ld16(w1 + (size_t)(n0 + srow1)*528 + 256 + k0 + sq1*8, &BsQ[(size_t)(256+t)*8]);
    __syncthreads();
    bf16x8 a0 = *(const bf16x8*)&As[(wv*32 + lr)*32 + qq*8];
    bf16x8 a1 = *(const bf16x8*)&As[(wv*32 + 16 + lr)*32 + qq*8];
    #pragma unroll
    for (int j = 0; j < 8; j++){
      bf16x8 bp = *(const bf16x8*)&BsP[(j*16 + lr)*32 + qq*8];
      bf16x8 bq = *(const bf16x8*)&BsQ[(j*16 + lr)*32 + qq*8];
      accP[0][j] = __builtin_amdgcn_mfma_f32_16x16x32_bf16(a0, bp, accP[0][j], 0, 0, 0);
      accP[1][j] = __builtin_amdgcn_mfma_f32_16x16x32_bf16(a1, bp, accP[1][j], 0, 0, 0);
      accQ[0][j] = __builtin_amdgcn_mfma_f32_16x16x32_bf16(a0, bq, accQ[0][j], 0, 0, 0);
      accQ[1][j] = __builtin_amdgcn_mfma_f32_16x16x32_bf16(a1, bq, accQ[1][j], 0, 0, 0);
    }
    __syncthreads();
  }
  #pragma unroll
  for (int f = 0; f < 2; f++){
    #pragma unroll
    for (int r = 0; r < 4; r++){
      int row = m0 + wv*32 + f*16 + qq*4 + r;
      if (row >= M) continue;
      #pragma unroll
      for (int j = 0; j < 8; j++){
        P[(size_t)row*Nc + n0 + j*16 + lr] = f2b(accP[f][j][r]);
        Q[(size_t)row*Nc + n0 + j*16 + lr] = f2b(accQ[f][j][r]);
      }
    }
  }
}

// ---------- 64xNc GEMM + bias + deg-mask + BN + relu (y-tiles folded) ------
// NJ = Nc/16 (16 for Od=256, 8 for Od=128); whole output width per block.
template<int NJ>
__global__ __launch_bounds__(256) void k_gemm_bn64(const ushort* __restrict__ A, int lda,
    const ushort* __restrict__ W, int ldb, int M, int Nc, int K,
    const void* __restrict__ bias, const void* __restrict__ g, const void* __restrict__ bb,
    const void* __restrict__ rm, const void* __restrict__ rv, const int* __restrict__ fflag,
    const int* __restrict__ rp, ushort* __restrict__ H){
  const int MT = (M + 63) >> 6;
  const int Tm = blockIdx.x;
  if (Tm >= MT) return;
  __shared__ ushort As[64*32];
  __shared__ ushort Bs[NJ*16*32];
  const int t = threadIdx.x;
  const int lane = t & 63;
  const int wv = t >> 6;
  const int m0 = Tm*64;
  const int lr = lane & 15;
  const int qq = lane >> 4;
  int srowA = t >> 2, sqA = t & 3;
  int ga = m0 + srowA; if (ga >= M) ga = M - 1;
  f32x4 acc[NJ];
  #pragma unroll
  for (int j = 0; j < NJ; j++) acc[j] = {0.f,0.f,0.f,0.f};
  for (int k0 = 0; k0 < K; k0 += 32){
    ld16(A + (size_t)ga*lda + k0 + sqA*8, &As[(size_t)t*8]);
    #pragma unroll
    for (int q = 0; q < NJ/4; q++)
      ld16(W + (size_t)((t>>2) + 64*q)*ldb + k0 + sqA*8, &Bs[(size_t)(t + 256*q)*8]);
    __syncthreads();
    bf16x8 a = *(const bf16x8*)&As[(wv*16 + lr)*32 + qq*8];
    #pragma unroll
    for (int j = 0; j < NJ; j++){
      bf16x8 b = *(const bf16x8*)&Bs[(j*16 + lr)*32 + qq*8];
      acc[j] = __builtin_amdgcn_mfma_f32_16x16x32_bf16(a, b, acc[j], 0, 0, 0);
    }
    __syncthreads();
  }
  int f = *fflag;
  float bi[NJ], sc[NJ], sh[NJ];
  #pragma unroll
  for (int j = 0; j < NJ; j++){
    int col = j*16 + lr;
    bi[j] = ldf(bias, f, col);
    sc[j] = ldf(g, f, col) * rsqrtf(ldf(rv, f, col) + 1e-5f);
    sh[j] = ldf(bb, f, col) - ldf(rm, f, col) * sc[j];
  }
  #pragma unroll
  for (int r = 0; r < 4; r++){
    int row = m0 + wv*16 + qq*4 + r;
    if (row >= M) continue;
    int empty = (rp[row+1] - rp[row] == 0);
    #pragma unroll
    for (int j = 0; j < NJ; j++){
      float v = acc[j][r] + bi[j];
      if (empty) v = 0.f;
      H[(size_t)row*Nc + j*16 + lr] = f2b(fmaxf(v*sc[j] + sh[j], 0.f));
    }
  }
}

// ---------- per-node edge aggregation (exact R15/R18 form, proven 68us) ----
template<int C>
__global__ __launch_bounds__(256) void k_msg4(const ushort* P, const ushort* __restrict__ Q,
    const float* __restrict__ ehp, const ushort* __restrict__ w1, const void* __restrict__ b1,
    const int* __restrict__ fflag, const int* __restrict__ rp, const int2* __restrict__ cpair,
    ushort* MU, int N){
  int t = threadIdx.x;
  int c0 = t*2;
  f32x2 wc[16];
  {
    float a0[16], a1[16];
    const uint4* wp0 = (const uint4*)(w1 + (size_t)c0*528 + 512);
    const uint4* wp1 = (const uint4*)(w1 + (size_t)(c0+1)*528 + 512);
    unpack8(wp0[0], a0); unpack8(wp0[1], a0+8);
    unpack8(wp1[0], a1); unpack8(wp1[1], a1+8);
    #pragma unroll
    for (int j = 0; j < 16; j++){ wc[j].x = a0[j]; wc[j].y = a1[j]; }
  }
  int ff = *fflag;
  f32x2 b1v = { ldf(b1, ff, c0), ldf(b1, ff, c0+1) };
  int nb = blockIdx.x*2;
  int ne = nb + 2; if (ne > N) ne = N;
  for (int n = nb; n < ne; n++){
    const int i0 = rp[n], i1 = rp[n+1];
    uint pw = *(const uint*)(P + (size_t)n*C + c0);
    f32x2 pre = { lo2f(pw) + b1v.x, hi2f(pw) + b1v.y };
    f32x2 acc0 = {0.f, 0.f}, acc1 = {0.f, 0.f};
    int i = i0;
    int2 p0, p1; uint qw0, qw1;
    if (i + 2 <= i1){
      p0 = cpair[i]; p1 = cpair[i+1];
      qw0 = *(const uint*)(Q + (size_t)p0.x*C + c0);
      qw1 = *(const uint*)(Q + (size_t)p1.x*C + c0);
    }
    while (i + 2 <= i1){
      int inx = i + 2;
      bool more = (inx + 2 <= i1);          // block-uniform branch
      int2 np0, np1;
      if (more){ np0 = cpair[inx]; np1 = cpair[inx+1]; }   // issue early
      const f32x4* e0p = (const f32x4*)(ehp + (size_t)i*16);
      const f32x4* e1p = (const f32x4*)(ehp + (size_t)(i+1)*16);
      f32x4 ea0 = e0p[0], ea1 = e0p[1], ea2 = e0p[2], ea3 = e0p[3];
      f32x4 eb0 = e1p[0], eb1 = e1p[1], eb2 = e1p[2], eb3 = e1p[3];
      uint nq0 = 0, nq1 = 0;
      if (more){
        nq0 = *(const uint*)(Q + (size_t)np0.x*C + c0);
        nq1 = *(const uint*)(Q + (size_t)np1.x*C + c0);
      }
      float ef0[16] = {ea0.x,ea0.y,ea0.z,ea0.w, ea1.x,ea1.y,ea1.z,ea1.w,
                       ea2.x,ea2.y,ea2.z,ea2.w, ea3.x,ea3.y,ea3.z,ea3.w};
      float ef1[16] = {eb0.x,eb0.y,eb0.z,eb0.w, eb1.x,eb1.y,eb1.z,eb1.w,
                       eb2.x,eb2.y,eb2.z,eb2.w, eb3.x,eb3.y,eb3.z,eb3.w};
      f32x2 d0 = { pre.x + lo2f(qw0), pre.y + hi2f(qw0) };
      f32x2 d1 = { pre.x + lo2f(qw1), pre.y + hi2f(qw1) };
      #pragma unroll
      for (int j = 0; j < 16; j++){
        f32x2 e0v = {ef0[j], ef0[j]};
        f32x2 e1v = {ef1[j], ef1[j]};
        d0 += wc[j] * e0v;
        d1 += wc[j] * e1v;
      }
      acc0.x += fmaxf(d0.x, 0.f); acc0.y += fmaxf(d0.y, 0.f);
      acc1.x += fmaxf(d1.x, 0.f); acc1.y += fmaxf(d1.y, 0.f);
      if (more){ p0 = np0; p1 = np1; qw0 = nq0; qw1 = nq1; }
      i = inx;
    }
    if (i < i1){
      int2 t0 = cpair[i];
      uint tq0 = *(const uint*)(Q + (size_t)t0.x*C + c0);
      const f32x4* e0p = (const f32x4*)(ehp + (size_t)i*16);
      f32x4 ea0 = e0p[0], ea1 = e0p[1], ea2 = e0p[2], ea3 = e0p[3];
      float ef0[16] = {ea0.x,ea0.y,ea0.z,ea0.w, ea1.x,ea1.y,ea1.z,ea1.w,
                       ea2.x,ea2.y,ea2.z,ea2.w, ea3.x,ea3.y,ea3.z,ea3.w};
      f32x2 d0 = { pre.x + lo2f(tq0), pre.y + hi2f(tq0) };
      #pragma unroll
      for (int j = 0; j < 16; j++){
        f32x2 e0v = {ef0[j], ef0[j]};
        d0 += wc[j] * e0v;
      }
      acc0.x += fmaxf(d0.x, 0.f); acc0.y += fmaxf(d0.y, 0.f);
    }
    int cnt = i1 - i0;
    float inv = (cnt > 0) ? 1.f/(float)cnt : 0.f;
    *(uint*)(MU + (size_t)n*C + c0) = pk2((acc0.x + acc1.x)*inv, (acc0.y + acc1.y)*inv);
  }
}

// ---------- pooling + FC + sigmoid (all params raw) ----------
__global__ __launch_bounds__(128) void k_pool(const ushort* __restrict__ h, const void* __restrict__ batch,
    const int* __restrict__ iflag, const void* __restrict__ fw, const void* __restrict__ fb,
    const int* __restrict__ fflag, void* __restrict__ out, int N){
  int g = blockIdx.x, t = threadIdx.x;
  int ifl = *iflag;
  int lo = 0, hi = N;
  while (lo < hi){ int mid = (lo+hi) >> 1; if (ld_idx(batch, ifl, mid) <  g) lo = mid+1; else hi = mid; }
  int s0 = lo;
  hi = N;
  while (lo < hi){ int mid = (lo+hi) >> 1; if (ld_idx(batch, ifl, mid) <= g) lo = mid+1; else hi = mid; }
  int s1 = lo;
  float s = 0.f;
  for (int i = s0; i < s1; i++) s += b2f(h[(size_t)i*128 + t]);
  int cnt = s1 - s0;
  __shared__ float ps[128];
  ps[t] = s / (float)(cnt > 0 ? cnt : 1);
  __syncthreads();
  int f = *fflag;
  if (t < 12){
    float z = ldf(fb, f, t);
    for (int j = 0; j < 128; j++) z += ps[j]*ldf(fw, f, t*128 + j);
    float r = 1.f/(1.f + expf(-z));
    if (f) ((float*)out)[g*12 + t] = r;
    else   ((ushort*)out)[g*12 + t] = f2b(r);
  }
}

__global__ __launch_bounds__(256) void k_sentinel(ushort* __restrict__ out, int n){
  int i = blockIdx.x*256 + threadIdx.x;
  if (i < n) out[i] = 0x3F00;
}

extern "C" void kernel_launch(void* const* d_in, const int* in_sizes, int n_in,
                              void* d_out, int out_size, void* d_ws, size_t ws_size,
                              hipStream_t stream){
  const void* x_raw   = d_in[0];
  const void* ei_raw  = d_in[1];
  const void* ea_raw  = d_in[2];
  const void* ba_raw  = d_in[3];
  (void)n_in;

  const int N = in_sizes[3];        // 20000
  const int E = in_sizes[1] / 2;    // 200000
  const int G = out_size / 12;      // 512

  // ---- workspace plan ----
  char* base = (char*)d_ws;
  size_t off = 0;
  auto alloc = [&](size_t bytes)->char*{
    char* p = base + off;
    off = (off + bytes + 255) & ~(size_t)255;
    return p;
  };
  int* iflag    = (int*)alloc(256);
  int* fflag    = (int*)alloc(256);
  int* deg      = (int*)alloc((size_t)N*4);
  int* fill     = (int*)alloc((size_t)N*4);   // contiguous-ish after deg
  int zn        = (int)(fill - deg) + N;      // ints to zero covering both
  int* rp       = (int*)alloc((size_t)(N+1)*4);
  int2* cpair   = (int2*)alloc((size_t)E*8);
  ushort* w1c[3], *w2c[3];
  const int w1n[3] = {512*528, 512*528, 256*528};
  const int w2n[3] = {256*512, 256*512, 128*256};
  for (int i = 0; i < 3; i++) w1c[i] = (ushort*)alloc((size_t)w1n[i]*2);
  for (int i = 0; i < 3; i++) w2c[i] = (ushort*)alloc((size_t)w2n[i]*2);
  float*  ehp32 = (float*)alloc((size_t)E*16*4);    // 12.8 MB, CSR-pos order
  ushort* h     = (ushort*)alloc((size_t)N*256*2);
  ushort* Q     = (ushort*)alloc((size_t)N*512*2);
  ushort* PM    = (ushort*)alloc((size_t)N*512*2);

  if (off > ws_size){
    k_sentinel<<<(out_size + 255)/256, 256, 0, stream>>>((ushort*)d_out, out_size);
    return;
  }

  // ---- zero+probe, count, scan ----
  k_zero_probe<<<(zn + 255)/256, 256, 0, stream>>>((const uint*)ei_raw, (const uint*)x_raw,
                                                   iflag, fflag, deg, zn);
  k_count<<<(E + 255)/256, 256, 0, stream>>>(ei_raw, iflag, deg, E, N);
  k_scan<<<1, 1024, 0, stream>>>(deg, rp, N);

  // ---- mega: fill + weight cvt + node-enc ----
  CvtTab ct; ct.nseg = 6;
  const void* csrcs[6] = {d_in[8], d_in[16], d_in[24], d_in[10], d_in[18], d_in[26]};
  ushort* cdsts[6]     = {w1c[0],  w1c[1],   w1c[2],   w2c[0],   w2c[1],   w2c[2]};
  const int cns[6]     = {w1n[0],  w1n[1],   w1n[2],   w2n[0],   w2n[1],   w2n[2]};
  int bacc = 0;
  for (int i = 0; i < 6; i++){
    ct.src[i] = csrcs[i]; ct.dst[i] = cdsts[i]; ct.n[i] = cns[i];
    ct.bstart[i] = bacc; bacc += (cns[i] + 8191)/8192;
  }
  int FB = (E + 255)/256;
  int CB = bacc;
  int NB = (N + 3)/4;
  k_mega<<<FB + CB + NB, 256, 0, stream>>>(
      ei_raw, iflag, rp, fill, cpair, ct, fflag,
      x_raw, d_in[6], d_in[7], h, E, N, FB, CB);

  // ---- fused edge-encode + reorder -> ehp (CSR order) ----
  k_edge<<<(E + 255)/256, 256, 0, stream>>>(cpair, ea_raw, d_in[4], d_in[5],
                                            fflag, ehp32, E);

  // ---- 3 conv layers ----
  const int Cch[3] = {512, 512, 256};
  const int Od[3]  = {256, 256, 128};
  const int MTpq = (N + 127)/128;
  const int MTbn = (N + 63)/64;
  for (int i = 0; i < 3; i++){
    int di = 8 + 8*i;
    int g1 = 8 * ((MTpq + 7)/8) * (Cch[i] >> 7);
    k_gemm_pq2<<<g1, 256, 0, stream>>>(h, w1c[i], N, Cch[i], PM, Q);
    dim3 gm((N + 1)/2);
    if (i < 2) k_msg4<512><<<gm, 256, 0, stream>>>(PM, Q, ehp32, w1c[i], d_in[di+1], fflag, rp, cpair, PM, N);
    else       k_msg4<256><<<gm, 128, 0, stream>>>(PM, Q, ehp32, w1c[i], d_in[di+1], fflag, rp, cpair, PM, N);
    int g2 = MTbn;   // y-tiles folded into one block
    if (i < 2) k_gemm_bn64<16><<<g2, 256, 0, stream>>>(PM, Cch[i], w2c[i], Cch[i], N, Od[i], Cch[i],
                                        d_in[di+3], d_in[di+4], d_in[di+5],
                                        d_in[di+6], d_in[di+7], fflag, rp, h);
    else       k_gemm_bn64<8><<<g2, 256, 0, stream>>>(PM, Cch[i], w2c[i], Cch[i], N, Od[i], Cch[i],
                                        d_in[di+3], d_in[di+4], d_in[di+5],
                                        d_in[di+6], d_in[di+7], fflag, rp, h);
  }

  // ---- mean pool + FC + sigmoid ----
  k_pool<<<G, 128, 0, stream>>>(h, ba_raw, iflag, d_in[32], d_in[33], fflag, d_out, N);
}

// Round 8
// 480.626 us; speedup vs baseline: 1.1356x; 1.1356x over previous
//
// GCNTox21 fused pipeline — MI355X/gfx950.  R20.
// R19 post-mortem: GEMM "density" (pq2 merge, bn64 y-fold) REGRESSED +61us
// — 128-VGPR acc + 313-block grids starved occupancy; for these short-K
// GEMMs parallelism > per-block density.  Reverted to R18 forms (proven).
// R20 lever: msg4 pipeline split.  R18's loop had cpair[i+2] -> Q[np.x]
// DEPENDENT within one iteration (~100-200cy serialized per 2-edge body)
// and Q only ~1 body ahead of use.  New: 2-pair index queue; per iter
// issue cpair for pair j+4 (independent) and Q for pair j+2 from indices
// loaded 2 iters ago; compute pair j with Q issued 2 bodies ago.
// Accumulation order bit-identical.  Everything else verbatim R18.
#include <hip/hip_runtime.h>
#include <hip/hip_bf16.h>

typedef unsigned int  uint;
typedef unsigned short ushort;
typedef float  f32x2  __attribute__((ext_vector_type(2)));
typedef float  f32x4  __attribute__((ext_vector_type(4)));
typedef __bf16 bf16x8 __attribute__((ext_vector_type(8)));

#define DEV static __device__ __forceinline__

DEV float  b2f(ushort b){ return __uint_as_float(((uint)b) << 16); }
DEV float  lo2f(uint u){ return __uint_as_float(u << 16); }
DEV float  hi2f(uint u){ return __uint_as_float(u & 0xffff0000u); }
DEV ushort f2b(float f){           // RNE float->bf16
  uint u = __float_as_uint(f);
  u += 0x7fffu + ((u >> 16) & 1u);
  return (ushort)(u >> 16);
}
DEV uint pk2(float a, float b){ return (uint)f2b(a) | ((uint)f2b(b) << 16); }
DEV void unpack8(uint4 v, float* f){
  f[0]=lo2f(v.x); f[1]=hi2f(v.x); f[2]=lo2f(v.y); f[3]=hi2f(v.y);
  f[4]=lo2f(v.z); f[5]=hi2f(v.z); f[6]=lo2f(v.w); f[7]=hi2f(v.w);
}
DEV int ld_idx(const void* p, int flag, long long i){
  return flag ? ((const int*)p)[i] : (int)((const long long*)p)[i];
}
DEV float ldf(const void* p, int f, int i){
  return f ? ((const float*)p)[i] : b2f(((const ushort*)p)[i]);
}
DEV int clampi(int v, int lo, int hi){ return v < lo ? lo : (v > hi ? hi : v); }

// async 16B global -> LDS (DMA).  LDS dest = wave-uniform base + lane*16.
DEV void ld16(const ushort* g, ushort* l){
  __builtin_amdgcn_global_load_lds(
      (const __attribute__((address_space(1))) void*)g,
      (__attribute__((address_space(3))) void*)l, 16, 0, 0);
}

// ---------- zero (deg+fill) + probes in one launch ----------
__global__ __launch_bounds__(256) void k_zero_probe(const uint* __restrict__ ei,
    const uint* __restrict__ xw, int* __restrict__ iflag, int* __restrict__ fflag,
    int* __restrict__ zbase, int zn){
  int i = blockIdx.x*256 + threadIdx.x;
  if (i < zn) zbase[i] = 0;
  if (blockIdx.x == 0){
    __shared__ int anyI, cntF;
    if (threadIdx.x == 0){ anyI = 0; cntF = 0; }
    __syncthreads();
    int li = 0, lc = 0;
    for (int k = threadIdx.x; k < 1024; k += 256){
      if (ei[2*k + 1] != 0u) li = 1;            // int64 => odd words all 0
      float f = fabsf(__uint_as_float(xw[k]));  // fp32 N(0,1) words decode sane
      if (f > 1e-6f && f < 1e6f) lc++;
    }
    if (li) atomicOr(&anyI, 1);
    atomicAdd(&cntF, lc);
    __syncthreads();
    if (threadIdx.x == 0){ *iflag = anyI; *fflag = (2*cntF > 1024) ? 1 : 0; }
  }
}

// ---------- CSR count + scan ----------
__global__ __launch_bounds__(256) void k_count(const void* __restrict__ ei,
    const int* __restrict__ flag, int* __restrict__ cnt, int E, int N){
  int e = blockIdx.x*256 + threadIdx.x;
  if (e >= E) return;
  int d = clampi(ld_idx(ei, *flag, (long long)E + e), 0, N-1);
  atomicAdd(&cnt[d], 1);
}

__global__ __launch_bounds__(1024) void k_scan(const int* __restrict__ deg, int* __restrict__ rp, int n){
  __shared__ int part[1024];
  int t = threadIdx.x;
  int chunk = (n + 1023) >> 10;
  int base = t * chunk;
  int s = 0;
  for (int i = 0; i < chunk; i++){ int j = base + i; if (j < n) s += deg[j]; }
  part[t] = s;
  __syncthreads();
  for (int off = 1; off < 1024; off <<= 1){
    int v = (t >= off) ? part[t - off] : 0;
    __syncthreads();
    part[t] += v;
    __syncthreads();
  }
  int run = part[t] - s;
  for (int i = 0; i < chunk; i++){ int j = base + i; if (j < n){ rp[j] = run; run += deg[j]; } }
  if (t == 1023) rp[n] = part[1023];
}

// ---------- mega: CSR-fill + weight-cvt + node-enc ----------
struct CvtTab { const void* src[6]; ushort* dst[6]; int n[6]; int bstart[6]; int nseg; };

__global__ __launch_bounds__(256) void k_mega(
    const void* __restrict__ ei, const int* __restrict__ iflag,
    const int* __restrict__ rp, int* __restrict__ fill, int2* __restrict__ cpair,
    CvtTab ct, const int* __restrict__ fflag,
    const void* __restrict__ x, const void* __restrict__ nw, const void* __restrict__ nbias,
    ushort* __restrict__ h,
    int E, int N, int FB, int CB){
  int b = blockIdx.x;
  int t = threadIdx.x;
  if (b < FB){
    // ---- CSR fill ----
    int e = b*256 + t;
    if (e >= E) return;
    int f = *iflag;
    int s = clampi(ld_idx(ei, f, e), 0, N-1);
    int d = clampi(ld_idx(ei, f, (long long)E + e), 0, N-1);
    int pos = clampi(rp[d] + atomicAdd(&fill[d], 1), 0, E-1);
    cpair[pos] = make_int2(s, e);
  } else if (b < FB + CB){
    // ---- weight conversion (w1 x3, w2 x3) ----
    int cb = b - FB;
    int s = ct.nseg - 1;
    for (int i = 1; i < ct.nseg; i++) if (cb < ct.bstart[i]){ s = i - 1; break; }
    int rel = cb - ct.bstart[s];
    const void* sp = ct.src[s];
    ushort* d = ct.dst[s];
    int f = *fflag;
    int end = ct.n[s]; int cap = rel*8192 + 8192; if (cap < end) end = cap;
    for (int i = rel*8192 + t; i < end; i += 256)
      d[i] = f ? f2b(((const float*)sp)[i]) : ((const ushort*)sp)[i];
  } else {
    // ---- node encoder: h = relu(x @ nw.T + nb), 4 nodes/block ----
    __shared__ float xs[4][32];
    int f = *fflag;
    int nb = (b - FB - CB)*4;
    if (t < 128){
      int ni = t >> 5, ci = t & 31;
      int n = nb + ni; if (n >= N) n = N - 1;
      xs[ni][ci] = f ? ((const float*)x)[(size_t)n*32 + ci]
                     : b2f(((const ushort*)x)[(size_t)n*32 + ci]);
    }
    __syncthreads();
    float wr[32];
    if (f){
      const float4* wp = (const float4*)((const float*)nw + (size_t)t*32);
      #pragma unroll
      for (int q4 = 0; q4 < 8; q4++){
        float4 v = wp[q4];
        wr[q4*4+0]=v.x; wr[q4*4+1]=v.y; wr[q4*4+2]=v.z; wr[q4*4+3]=v.w;
      }
    } else {
      const uint4* wp = (const uint4*)((const ushort*)nw + (size_t)t*32);
      unpack8(wp[0], wr); unpack8(wp[1], wr+8); unpack8(wp[2], wr+16); unpack8(wp[3], wr+24);
    }
    float bv = ldf(nbias, f, t);
    #pragma unroll
    for (int ni = 0; ni < 4; ni++){
      int n = nb + ni;
      if (n >= N) break;
      float s = bv;
      #pragma unroll
      for (int k = 0; k < 32; k++) s += xs[ni][k]*wr[k];
      h[(size_t)n*256 + t] = f2b(fmaxf(s, 0.f));
    }
  }
}

// ---------- fused edge-encoder + reorder ----------
__global__ __launch_bounds__(256) void k_edge(const int2* __restrict__ cpair,
    const void* __restrict__ ea, const void* __restrict__ eew, const void* __restrict__ eeb,
    const int* __restrict__ fflag, float* __restrict__ ehp, int E){
  __shared__ float ws[128];
  __shared__ float bs[16];
  int f = *fflag;
  int t = threadIdx.x;
  if (t < 128) ws[t] = ldf(eew, f, t);
  if (t < 16)  bs[t] = ldf(eeb, f, t);
  __syncthreads();
  int pos = blockIdx.x*256 + t;
  if (pos >= E) return;
  int e = cpair[pos].y;
  float a[8];
  if (f){
    const float4* ap = (const float4*)((const float*)ea + (size_t)e*8);
    float4 v0 = ap[0], v1 = ap[1];
    a[0]=v0.x; a[1]=v0.y; a[2]=v0.z; a[3]=v0.w;
    a[4]=v1.x; a[5]=v1.y; a[6]=v1.z; a[7]=v1.w;
  } else {
    uint4 av = *(const uint4*)((const ushort*)ea + (size_t)e*8);
    unpack8(av, a);
  }
  float o[16];
  #pragma unroll
  for (int c = 0; c < 16; c++){
    float s = bs[c];
    #pragma unroll
    for (int j = 0; j < 8; j++) s += a[j]*ws[c*8+j];
    o[c] = fmaxf(s, 0.f);
  }
  f32x4* op = (f32x4*)(ehp + (size_t)pos*16);
  #pragma unroll
  for (int q4 = 0; q4 < 4; q4++){
    f32x4 v = {o[q4*4+0], o[q4*4+1], o[q4*4+2], o[q4*4+3]};
    op[q4] = v;
  }
}

// ---------- LDS-staged 128x128 GEMM: P/Q producer (R18 exact, proven) ------
__global__ __launch_bounds__(256) void k_gemm_pq_lds(const ushort* __restrict__ A,
    const ushort* __restrict__ w1, int M, int Nc,
    ushort* __restrict__ P, ushort* __restrict__ Q){
  const int MT = (M + 127) >> 7;
  const int YC = Nc >> 6;            // total y-variants: 8 (C=512) / 4 (C=256)
  int jb = blockIdx.x;
  int gx = jb & 7, rr = jb >> 3;
  int sx = rr / YC, yy = rr % YC;
  const int Tm = sx*8 + gx;
  if (Tm >= MT) return;
  __shared__ ushort As[128*32];
  __shared__ ushort Bs[128*32];
  const int t = threadIdx.x;
  const int lane = t & 63;
  const int wv = t >> 6;
  const int m0 = Tm*128;
  const int yc = Nc >> 7;
  const int isQ = yy >= yc;
  const int n0 = (isQ ? yy - yc : yy)*128;
  const ushort* W = w1 + (isQ ? 256 : 0);
  ushort* C = isQ ? Q : P;
  const int lr = lane & 15;
  const int qq = lane >> 4;
  int srow0 = t >> 2,         sq0 = t & 3;
  int srow1 = (256 + t) >> 2, sq1 = t & 3;
  int ga0 = m0 + srow0; if (ga0 >= M) ga0 = M - 1;
  int ga1 = m0 + srow1; if (ga1 >= M) ga1 = M - 1;
  f32x4 acc[2][8];
  #pragma unroll
  for (int f = 0; f < 2; f++)
    #pragma unroll
    for (int j = 0; j < 8; j++) acc[f][j] = {0.f,0.f,0.f,0.f};
  for (int k0 = 0; k0 < 256; k0 += 32){
    ld16(A + (size_t)ga0*256 + k0 + sq0*8, &As[(size_t)t*8]);
    ld16(A + (size_t)ga1*256 + k0 + sq1*8, &As[(size_t)(256+t)*8]);
    ld16(W + (size_t)(n0 + srow0)*528 + k0 + sq0*8, &Bs[(size_t)t*8]);
    ld16(W + (size_t)(n0 + srow1)*528 + k0 + sq1*8, &Bs[(size_t)(256+t)*8]);
    __syncthreads();
    bf16x8 a0 = *(const bf16x8*)&As[(wv*32 + lr)*32 + qq*8];
    bf16x8 a1 = *(const bf16x8*)&As[(wv*32 + 16 + lr)*32 + qq*8];
    #pragma unroll
    for (int j = 0; j < 8; j++){
      bf16x8 b = *(const bf16x8*)&Bs[(j*16 + lr)*32 + qq*8];
      acc[0][j] = __builtin_amdgcn_mfma_f32_16x16x32_bf16(a0, b, acc[0][j], 0, 0, 0);
      acc[1][j] = __builtin_amdgcn_mfma_f32_16x16x32_bf16(a1, b, acc[1][j], 0, 0, 0);
    }
    __syncthreads();
  }
  #pragma unroll
  for (int f = 0; f < 2; f++){
    #pragma unroll
    for (int r = 0; r < 4; r++){
      int row = m0 + wv*32 + f*16 + qq*4 + r;
      if (row >= M) continue;
      #pragma unroll
      for (int j = 0; j < 8; j++)
        C[(size_t)row*Nc + n0 + j*16 + lr] = f2b(acc[f][j][r]);
    }
  }
}

// ---------- LDS-staged 64x128 GEMM + bias + deg-mask + BN + relu (R18 exact) --
__global__ __launch_bounds__(256) void k_gemm_bn64(const ushort* __restrict__ A, int lda,
    const ushort* __restrict__ W, int ldb, int M, int Nc, int K,
    const void* __restrict__ bias, const void* __restrict__ g, const void* __restrict__ bb,
    const void* __restrict__ rm, const void* __restrict__ rv, const int* __restrict__ fflag,
    const int* __restrict__ rp, ushort* __restrict__ H){
  const int MT = (M + 63) >> 6;
  const int YC = Nc >> 7;            // 2 (Od=256) / 1 (Od=128)
  int jb = blockIdx.x;
  int gx = jb & 7, rr = jb >> 3;
  int sx = rr / YC, yy = rr % YC;
  const int Tm = sx*8 + gx;
  if (Tm >= MT) return;
  __shared__ ushort As[64*32];
  __shared__ ushort Bs[128*32];
  const int t = threadIdx.x;
  const int lane = t & 63;
  const int wv = t >> 6;
  const int m0 = Tm*64;
  const int n0 = yy*128;
  const int lr = lane & 15;
  const int qq = lane >> 4;
  int srowA = t >> 2, sqA = t & 3;
  int ga = m0 + srowA; if (ga >= M) ga = M - 1;
  int srowB0 = t >> 2,        srowB1 = 64 + (t >> 2);
  f32x4 acc[8];
  #pragma unroll
  for (int j = 0; j < 8; j++) acc[j] = {0.f,0.f,0.f,0.f};
  for (int k0 = 0; k0 < K; k0 += 32){
    ld16(A + (size_t)ga*lda + k0 + sqA*8, &As[(size_t)t*8]);
    ld16(W + (size_t)(n0 + srowB0)*ldb + k0 + sqA*8, &Bs[(size_t)t*8]);
    ld16(W + (size_t)(n0 + srowB1)*ldb + k0 + sqA*8, &Bs[(size_t)(256+t)*8]);
    __syncthreads();
    bf16x8 a = *(const bf16x8*)&As[(wv*16 + lr)*32 + qq*8];
    #pragma unroll
    for (int j = 0; j < 8; j++){
      bf16x8 b = *(const bf16x8*)&Bs[(j*16 + lr)*32 + qq*8];
      acc[j] = __builtin_amdgcn_mfma_f32_16x16x32_bf16(a, b, acc[j], 0, 0, 0);
    }
    __syncthreads();
  }
  int f = *fflag;
  float bi[8], sc[8], sh[8];
  #pragma unroll
  for (int j = 0; j < 8; j++){
    int col = n0 + j*16 + lr;
    bi[j] = ldf(bias, f, col);
    sc[j] = ldf(g, f, col) * rsqrtf(ldf(rv, f, col) + 1e-5f);
    sh[j] = ldf(bb, f, col) - ldf(rm, f, col) * sc[j];
  }
  #pragma unroll
  for (int r = 0; r < 4; r++){
    int row = m0 + wv*16 + qq*4 + r;
    if (row >= M) continue;
    int empty = (rp[row+1] - rp[row] == 0);
    #pragma unroll
    for (int j = 0; j < 8; j++){
      float v = acc[j][r] + bi[j];
      if (empty) v = 0.f;
      H[(size_t)row*Nc + n0 + j*16 + lr] = f2b(fmaxf(v*sc[j] + sh[j], 0.f));
    }
  }
}

// ---------- per-node edge aggregation (R20: split 2-deep pipeline) ----------
// 2 nodes/block; thread t owns channels {2t,2t+1}; 2-edge (1-pair) body.
// Index queue ic/id (pairs j+2, j+3) decouples cpair->Q: per iteration
// issue cpair for pair j+4 and Q for pair j+2 (indices ready, no wait);
// compute pair j with Q issued 2 bodies ago.  Accumulation order identical
// to R15/R18.  MU may alias P (read-before-write per thread).
template<int C>
__global__ __launch_bounds__(256) void k_msg4(const ushort* P, const ushort* __restrict__ Q,
    const float* __restrict__ ehp, const ushort* __restrict__ w1, const void* __restrict__ b1,
    const int* __restrict__ fflag, const int* __restrict__ rp, const int2* __restrict__ cpair,
    ushort* MU, int N){
  int t = threadIdx.x;
  int c0 = t*2;
  f32x2 wc[16];
  {
    float a0[16], a1[16];
    const uint4* wp0 = (const uint4*)(w1 + (size_t)c0*528 + 512);
    const uint4* wp1 = (const uint4*)(w1 + (size_t)(c0+1)*528 + 512);
    unpack8(wp0[0], a0); unpack8(wp0[1], a0+8);
    unpack8(wp1[0], a1); unpack8(wp1[1], a1+8);
    #pragma unroll
    for (int j = 0; j < 16; j++){ wc[j].x = a0[j]; wc[j].y = a1[j]; }
  }
  int ff = *fflag;
  f32x2 b1v = { ldf(b1, ff, c0), ldf(b1, ff, c0+1) };
  int nb = blockIdx.x*2;
  int ne = nb + 2; if (ne > N) ne = N;
  for (int n = nb; n < ne; n++){
    const int i0 = rp[n], i1 = rp[n+1];
    uint pw = *(const uint*)(P + (size_t)n*C + c0);
    f32x2 pre = { lo2f(pw) + b1v.x, hi2f(pw) + b1v.y };
    f32x2 acc0 = {0.f, 0.f}, acc1 = {0.f, 0.f};
    const int np = (i1 - i0) >> 1;         // full pairs (block-uniform)
    const int2* cp = cpair + i0;
    // ---- prologue: Q for pairs 0,1 issued; indices for pairs 2,3 loaded --
    uint q0a = 0, q0b = 0, q1a = 0, q1b = 0;
    int2 ic0 = {0,0}, ic1 = {0,0}, id0 = {0,0}, id1 = {0,0};
    if (np > 0){
      int2 a0 = cp[0], a1 = cp[1];
      q0a = *(const uint*)(Q + (size_t)a0.x*C + c0);
      q0b = *(const uint*)(Q + (size_t)a1.x*C + c0);
    }
    if (np > 1){
      int2 b0 = cp[2], b1i = cp[3];
      q1a = *(const uint*)(Q + (size_t)b0.x*C + c0);
      q1b = *(const uint*)(Q + (size_t)b1i.x*C + c0);
    }
    if (np > 2){ ic0 = cp[4]; ic1 = cp[5]; }
    if (np > 3){ id0 = cp[6]; id1 = cp[7]; }
    for (int j = 0; j < np; j++){
      // issue cpair for pair j+4 (sequential, independent)
      int2 ne0 = {0,0}, ne1 = {0,0};
      if (j + 4 < np){ ne0 = cp[2*j + 8]; ne1 = cp[2*j + 9]; }
      // issue Q for pair j+2 from indices loaded 2 iterations ago (ready)
      uint qna = 0, qnb = 0;
      if (j + 2 < np){
        qna = *(const uint*)(Q + (size_t)ic0.x*C + c0);
        qnb = *(const uint*)(Q + (size_t)ic1.x*C + c0);
      }
      // ehp for pair j: sequential CSR-order stream
      const f32x4* e0p = (const f32x4*)(ehp + (size_t)(i0 + 2*j)*16);
      f32x4 ea0 = e0p[0], ea1 = e0p[1], ea2 = e0p[2], ea3 = e0p[3];
      f32x4 eb0 = e0p[4], eb1 = e0p[5], eb2 = e0p[6], eb3 = e0p[7];
      float ef0[16] = {ea0.x,ea0.y,ea0.z,ea0.w, ea1.x,ea1.y,ea1.z,ea1.w,
                       ea2.x,ea2.y,ea2.z,ea2.w, ea3.x,ea3.y,ea3.z,ea3.w};
      float ef1[16] = {eb0.x,eb0.y,eb0.z,eb0.w, eb1.x,eb1.y,eb1.z,eb1.w,
                       eb2.x,eb2.y,eb2.z,eb2.w, eb3.x,eb3.y,eb3.z,eb3.w};
      // compute pair j with Q issued 2 bodies ago
      f32x2 d0 = { pre.x + lo2f(q0a), pre.y + hi2f(q0a) };
      f32x2 d1 = { pre.x + lo2f(q0b), pre.y + hi2f(q0b) };
      #pragma unroll
      for (int k = 0; k < 16; k++){
        f32x2 e0v = {ef0[k], ef0[k]};
        f32x2 e1v = {ef1[k], ef1[k]};
        d0 += wc[k] * e0v;
        d1 += wc[k] * e1v;
      }
      acc0.x += fmaxf(d0.x, 0.f); acc0.y += fmaxf(d0.y, 0.f);
      acc1.x += fmaxf(d1.x, 0.f); acc1.y += fmaxf(d1.y, 0.f);
      // shift queues
      q0a = q1a; q0b = q1b; q1a = qna; q1b = qnb;
      ic0 = id0; ic1 = id1; id0 = ne0; id1 = ne1;
    }
    int i = i0 + 2*np;
    if (i < i1){
      // odd-degree tail: single edge, direct loads
      int2 t0 = cpair[i];
      uint tq0 = *(const uint*)(Q + (size_t)t0.x*C + c0);
      const f32x4* e0p = (const f32x4*)(ehp + (size_t)i*16);
      f32x4 ea0 = e0p[0], ea1 = e0p[1], ea2 = e0p[2], ea3 = e0p[3];
      float ef0[16] = {ea0.x,ea0.y,ea0.z,ea0.w, ea1.x,ea1.y,ea1.z,ea1.w,
                       ea2.x,ea2.y,ea2.z,ea2.w, ea3.x,ea3.y,ea3.z,ea3.w};
      f32x2 d0 = { pre.x + lo2f(tq0), pre.y + hi2f(tq0) };
      #pragma unroll
      for (int k = 0; k < 16; k++){
        f32x2 e0v = {ef0[k], ef0[k]};
        d0 += wc[k] * e0v;
      }
      acc0.x += fmaxf(d0.x, 0.f); acc0.y += fmaxf(d0.y, 0.f);
    }
    int cnt = i1 - i0;
    float inv = (cnt > 0) ? 1.f/(float)cnt : 0.f;
    *(uint*)(MU + (size_t)n*C + c0) = pk2((acc0.x + acc1.x)*inv, (acc0.y + acc1.y)*inv);
  }
}

// ---------- pooling + FC + sigmoid (all params raw) ----------
__global__ __launch_bounds__(128) void k_pool(const ushort* __restrict__ h, const void* __restrict__ batch,
    const int* __restrict__ iflag, const void* __restrict__ fw, const void* __restrict__ fb,
    const int* __restrict__ fflag, void* __restrict__ out, int N){
  int g = blockIdx.x, t = threadIdx.x;
  int ifl = *iflag;
  int lo = 0, hi = N;
  while (lo < hi){ int mid = (lo+hi) >> 1; if (ld_idx(batch, ifl, mid) <  g) lo = mid+1; else hi = mid; }
  int s0 = lo;
  hi = N;
  while (lo < hi){ int mid = (lo+hi) >> 1; if (ld_idx(batch, ifl, mid) <= g) lo = mid+1; else hi = mid; }
  int s1 = lo;
  float s = 0.f;
  for (int i = s0; i < s1; i++) s += b2f(h[(size_t)i*128 + t]);
  int cnt = s1 - s0;
  __shared__ float ps[128];
  ps[t] = s / (float)(cnt > 0 ? cnt : 1);
  __syncthreads();
  int f = *fflag;
  if (t < 12){
    float z = ldf(fb, f, t);
    for (int j = 0; j < 128; j++) z += ps[j]*ldf(fw, f, t*128 + j);
    float r = 1.f/(1.f + expf(-z));
    if (f) ((float*)out)[g*12 + t] = r;
    else   ((ushort*)out)[g*12 + t] = f2b(r);
  }
}

__global__ __launch_bounds__(256) void k_sentinel(ushort* __restrict__ out, int n){
  int i = blockIdx.x*256 + threadIdx.x;
  if (i < n) out[i] = 0x3F00;
}

extern "C" void kernel_launch(void* const* d_in, const int* in_sizes, int n_in,
                              void* d_out, int out_size, void* d_ws, size_t ws_size,
                              hipStream_t stream){
  const void* x_raw   = d_in[0];
  const void* ei_raw  = d_in[1];
  const void* ea_raw  = d_in[2];
  const void* ba_raw  = d_in[3];
  (void)n_in;

  const int N = in_sizes[3];        // 20000
  const int E = in_sizes[1] / 2;    // 200000
  const int G = out_size / 12;      // 512

  // ---- workspace plan ----
  char* base = (char*)d_ws;
  size_t off = 0;
  auto alloc = [&](size_t bytes)->char*{
    char* p = base + off;
    off = (off + bytes + 255) & ~(size_t)255;
    return p;
  };
  int* iflag    = (int*)alloc(256);
  int* fflag    = (int*)alloc(256);
  int* deg      = (int*)alloc((size_t)N*4);
  int* fill     = (int*)alloc((size_t)N*4);   // contiguous-ish after deg
  int zn        = (int)(fill - deg) + N;      // ints to zero covering both
  int* rp       = (int*)alloc((size_t)(N+1)*4);
  int2* cpair   = (int2*)alloc((size_t)E*8);
  ushort* w1c[3], *w2c[3];
  const int w1n[3] = {512*528, 512*528, 256*528};
  const int w2n[3] = {256*512, 256*512, 128*256};
  for (int i = 0; i < 3; i++) w1c[i] = (ushort*)alloc((size_t)w1n[i]*2);
  for (int i = 0; i < 3; i++) w2c[i] = (ushort*)alloc((size_t)w2n[i]*2);
  float*  ehp32 = (float*)alloc((size_t)E*16*4);    // 12.8 MB, CSR-pos order
  ushort* h     = (ushort*)alloc((size_t)N*256*2);
  ushort* Q     = (ushort*)alloc((size_t)N*512*2);
  ushort* PM    = (ushort*)alloc((size_t)N*512*2);

  if (off > ws_size){
    k_sentinel<<<(out_size + 255)/256, 256, 0, stream>>>((ushort*)d_out, out_size);
    return;
  }

  // ---- zero+probe, count, scan ----
  k_zero_probe<<<(zn + 255)/256, 256, 0, stream>>>((const uint*)ei_raw, (const uint*)x_raw,
                                                   iflag, fflag, deg, zn);
  k_count<<<(E + 255)/256, 256, 0, stream>>>(ei_raw, iflag, deg, E, N);
  k_scan<<<1, 1024, 0, stream>>>(deg, rp, N);

  // ---- mega: fill + weight cvt + node-enc ----
  CvtTab ct; ct.nseg = 6;
  const void* csrcs[6] = {d_in[8], d_in[16], d_in[24], d_in[10], d_in[18], d_in[26]};
  ushort* cdsts[6]     = {w1c[0],  w1c[1],   w1c[2],   w2c[0],   w2c[1],   w2c[2]};
  const int cns[6]     = {w1n[0],  w1n[1],   w1n[2],   w2n[0],   w2n[1],   w2n[2]};
  int bacc = 0;
  for (int i = 0; i < 6; i++){
    ct.src[i] = csrcs[i]; ct.dst[i] = cdsts[i]; ct.n[i] = cns[i];
    ct.bstart[i] = bacc; bacc += (cns[i] + 8191)/8192;
  }
  int FB = (E + 255)/256;
  int CB = bacc;
  int NB = (N + 3)/4;
  k_mega<<<FB + CB + NB, 256, 0, stream>>>(
      ei_raw, iflag, rp, fill, cpair, ct, fflag,
      x_raw, d_in[6], d_in[7], h, E, N, FB, CB);

  // ---- fused edge-encode + reorder -> ehp (CSR order) ----
  k_edge<<<(E + 255)/256, 256, 0, stream>>>(cpair, ea_raw, d_in[4], d_in[5],
                                            fflag, ehp32, E);

  // ---- 3 conv layers ----
  const int Cch[3] = {512, 512, 256};
  const int Od[3]  = {256, 256, 128};
  const int MTpq = (N + 127)/128;
  const int MTbn = (N + 63)/64;
  for (int i = 0; i < 3; i++){
    int di = 8 + 8*i;
    int g1 = 8 * ((MTpq + 7)/8) * (Cch[i] >> 6);
    k_gemm_pq_lds<<<g1, 256, 0, stream>>>(h, w1c[i], N, Cch[i], PM, Q);
    dim3 gm((N + 1)/2);
    if (i < 2) k_msg4<512><<<gm, 256, 0, stream>>>(PM, Q, ehp32, w1c[i], d_in[di+1], fflag, rp, cpair, PM, N);
    else       k_msg4<256><<<gm, 128, 0, stream>>>(PM, Q, ehp32, w1c[i], d_in[di+1], fflag, rp, cpair, PM, N);
    int g2 = 8 * ((MTbn + 7)/8) * (Od[i] >> 7);
    k_gemm_bn64<<<g2, 256, 0, stream>>>(PM, Cch[i], w2c[i], Cch[i], N, Od[i], Cch[i],
                                        d_in[di+3], d_in[di+4], d_in[di+5],
                                        d_in[di+6], d_in[di+7], fflag, rp, h);
  }

  // ---- mean pool + FC + sigmoid ----
  k_pool<<<G, 128, 0, stream>>>(h, ba_raw, iflag, d_in[32], d_in[33], fflag, d_out, N);
}